// Round 4
// baseline (16401.674 us; speedup 1.0000x reference)
//
#include <hip/hip_runtime.h>

#define T_STEPS 4096
#define HDIM 1024

typedef __bf16 bf16x8 __attribute__((ext_vector_type(8)));
typedef float f32x4 __attribute__((ext_vector_type(4)));

__device__ __forceinline__ unsigned short f2bf(float x) {
  unsigned u = __builtin_bit_cast(unsigned, x);
  u += 0x7fffu + ((u >> 16) & 1u);   // RNE
  return (unsigned short)(u >> 16);
}
__device__ __forceinline__ float bf2f(unsigned short b) {
  unsigned u = ((unsigned)b) << 16;
  return __builtin_bit_cast(float, u);
}

// ---------------------------------------------------------------------------
// Kernel 1: build xs_bf16 [2][4096][2048] from res_for / res_back.
// ---------------------------------------------------------------------------
__global__ __launch_bounds__(256) void build_xs(
    const float* __restrict__ rf, const float* __restrict__ rb,
    unsigned short* __restrict__ xs) {
  int idx = blockIdx.x * 256 + threadIdx.x;   // one thread per 4 elems
  int e = idx * 4;
  int f = e & 2047;
  int td = e >> 11;
  int t = td & 4095;
  int d = td >> 12;
  bool lower = f < 1024;
  int f2 = f & 1023;
  int trow;
  if (d == 0) trow = lower ? t : (4095 - t);
  else        trow = lower ? (4095 - t) : t;
  const float* src = (lower ? rf : rb) + trow * 1024 + f2;
  float4 v = *(const float4*)src;
  ushort4 o = make_ushort4(f2bf(v.x), f2bf(v.y), f2bf(v.z), f2bf(v.w));
  *(ushort4*)(xs + e) = o;
}

// ---------------------------------------------------------------------------
// Kernel 2: wxT_bf16 [4096 g][2048 f] = transpose of w[:2048].
// ---------------------------------------------------------------------------
__global__ __launch_bounds__(256) void transpose_wx(
    const float* __restrict__ w, unsigned short* __restrict__ wxT) {
  __shared__ float tile[64][65];
  int bid = blockIdx.x;          // 2048 = 32 (f) * 64 (g)
  int bf_ = bid / 64;
  int bg = bid % 64;
  int f0 = bf_ * 64, g0 = bg * 64;
  int tid = threadIdx.x;
#pragma unroll
  for (int s = 0; s < 16; ++s) {
    int idx = s * 256 + tid;
    int fl = idx >> 6, gl = idx & 63;
    tile[fl][gl] = w[(size_t)(f0 + fl) * 4096 + g0 + gl];
  }
  __syncthreads();
#pragma unroll
  for (int s = 0; s < 16; ++s) {
    int idx = s * 256 + tid;
    int gl = idx >> 6, fl = idx & 63;
    wxT[(size_t)(g0 + gl) * 2048 + f0 + fl] = f2bf(tile[fl][gl]);
  }
}

// ---------------------------------------------------------------------------
// Kernel 3: zx = xs @ wx -> bf16 [8192][4096]. 128x128 tile, BK=32, 4 waves.
// ---------------------------------------------------------------------------
__global__ __launch_bounds__(256) void gemm_zx(
    const unsigned short* __restrict__ xs, const unsigned short* __restrict__ wxT,
    unsigned short* __restrict__ zxo) {
  __shared__ uint4 lds[1024];   // A: bytes [0,8192), B: [8192,16384)
  char* ldsb = (char*)lds;
  int bid = blockIdx.x;
  int by = bid >> 5;
  int bx = bid & 31;
  int tid = threadIdx.x, lane = tid & 63, wid = tid >> 6;
  int wr = wid >> 1, wc = wid & 1;
  const int arow0 = by * 128, bcol0 = bx * 128;

  f32x4 acc[4][4] = {};

  for (int kt = 0; kt < 64; ++kt) {
    int k0 = kt * 32;
#pragma unroll
    for (int s = 0; s < 2; ++s) {
      int c = tid + 256 * s;
      int L = c * 16;
      int P = L ^ (((L >> 6) & 7) << 4);
      int row = c >> 2, ko = (c & 3) * 8;
      uint4 av = *(const uint4*)(xs  + (size_t)(arow0 + row) * 2048 + k0 + ko);
      uint4 bv = *(const uint4*)(wxT + (size_t)(bcol0 + row) * 2048 + k0 + ko);
      *(uint4*)(ldsb + P) = av;
      *(uint4*)(ldsb + 8192 + P) = bv;
    }
    __syncthreads();

    bf16x8 afr[4], bfr[4];
#pragma unroll
    for (int i = 0; i < 4; ++i) {
      int arow = wr * 64 + i * 16 + (lane & 15);
      int L = arow * 64 + (lane >> 4) * 16;
      int P = L ^ ((arow & 7) << 4);
      afr[i] = *(bf16x8*)(ldsb + P);
      int brow = wc * 64 + i * 16 + (lane & 15);
      int L2 = brow * 64 + (lane >> 4) * 16;
      int P2 = L2 ^ ((brow & 7) << 4);
      bfr[i] = *(bf16x8*)(ldsb + 8192 + P2);
    }
#pragma unroll
    for (int mi = 0; mi < 4; ++mi)
#pragma unroll
      for (int ni = 0; ni < 4; ++ni)
        acc[mi][ni] = __builtin_amdgcn_mfma_f32_16x16x32_bf16(
            afr[mi], bfr[ni], acc[mi][ni], 0, 0, 0);
    __syncthreads();
  }

#pragma unroll
  for (int mi = 0; mi < 4; ++mi)
#pragma unroll
    for (int ni = 0; ni < 4; ++ni)
#pragma unroll
      for (int r = 0; r < 4; ++r) {
        int rrow = arow0 + wr * 64 + mi * 16 + (lane >> 4) * 4 + r;
        int col  = bcol0 + wc * 64 + ni * 16 + (lane & 15);
        zxo[(size_t)rrow * 4096 + col] = f2bf(acc[mi][ni][r]);
      }
}

// ---------------------------------------------------------------------------
// Kernel 3.5: clear hcom tags (aliases dead xs region; runs after gemm).
// ---------------------------------------------------------------------------
__global__ __launch_bounds__(256) void clear_hcom(uint4* __restrict__ p) {
  p[(size_t)blockIdx.x * 256 + threadIdx.x] = uint4{0, 0, 0, 0};
}

// ---------------------------------------------------------------------------
// Kernel 4: persistent recurrent LSTM. 128 blocks (64/dir) x 1024 threads.
// Step structure (one barrier, no wave0 tail):
//   - wave w polls its own 64-element k-slice of packed h (poll IS the load)
//   - in-register broadcast via v_readlane feeding v_fmac (no LDS h-stage)
//   - part[16][64] partials (stride-68 pad), ONE barrier
//   - wave w owns row j=jbase+w: lane(q,gi) reads part[q][gi*16+w],
//     4-level shfl_xor tree over q, per-gi nonlin, readlane gates ->
//     uniform c/h per wave, lane0 fire-and-forget stores.
// ---------------------------------------------------------------------------
__device__ __forceinline__ float sigm(float x) {
  return 1.0f / (1.0f + __expf(-x));
}
__device__ __forceinline__ float tanh_fast(float x) {
  float e = __expf(-2.0f * x);
  return (1.0f - e) / (1.0f + e);
}
__device__ __forceinline__ float rlane(float v, int l) {
  return __builtin_bit_cast(float,
      __builtin_amdgcn_readlane(__builtin_bit_cast(int, v), l));
}

__global__ __launch_bounds__(1024, 4) void lstm_rec(
    const unsigned short* __restrict__ zx,  // [2][4096][4096] bf16
    const float* __restrict__ w,            // [3072][4096] f32 (w_h = rows 2048+)
    float* __restrict__ hout,               // d_out [2][4096][1024] f32
    unsigned* __restrict__ hcom) {          // [2][4096][1024] packed tag|bf16h
  __shared__ float part[2][16][68];         // stride-68: 2-way bank alias only

  int bid = blockIdx.x;
  int dir = bid >> 6;
  int bslot = bid & 63;
  int jbase = bslot << 4;                   // 16 j's per block, wave w owns j=jbase+w
  int tid = threadIdx.x;
  int wave = tid >> 6;                      // k-slice [wave*64, wave*64+64)
  int lane = tid & 63;
  int jj = lane & 15, g = lane >> 4;        // matvec col = g*16+jj
  int gcol = (g << 10) + jbase + jj;
  int q = lane >> 2, gi = lane & 3;         // reduce role: q-chunk, gate

  // W_h slice: w[(2048 + wave*64 + p)][gcol], p = 0..63 (f32, exact)
  float wreg[64];
#pragma unroll
  for (int p = 0; p < 64; ++p)
    wreg[p] = w[(size_t)(2048 + wave * 64 + p) * 4096 + gcol];
#pragma unroll
  for (int p = 0; p < 64; ++p) asm volatile("" : "+v"(wreg[p]));

  float c_reg = 0.0f;
  const unsigned short* zrow = zx + (size_t)dir * T_STEPS * 4096;
  float* hrow = hout + (size_t)dir * T_STEPS * HDIM;
  unsigned* hcd = hcom + (size_t)dir * T_STEPS * HDIM;

  for (int t = 0; t < T_STEPS; ++t) {
    // zx for this wave's j: 4 gate values, same addr per gi-class (broadcast)
    float zxv = bf2f(zrow[(size_t)t * 4096 + (gi << 10) + jbase + wave]);

    // poll own k-slice of h_{t-1}; tag monotone {0, t<<16|bf16} so (< want) works
    unsigned pv = 0;
    float a0 = 0.f, a1 = 0.f, a2 = 0.f, a3 = 0.f;
    if (t > 0) {
      const unsigned* hp = hcd + (size_t)(t - 1) * HDIM + wave * 64 + lane;
      unsigned want = (unsigned)t << 16;
      do {
        pv = __hip_atomic_load(hp, __ATOMIC_RELAXED, __HIP_MEMORY_SCOPE_AGENT);
      } while (pv < want);
      unsigned hb = pv << 16;               // f32 bits of h[wave*64+lane]
      // in-register broadcast matvec: readlane -> sgpr feeds v_fmac
#pragma unroll
      for (int p = 0; p < 64; p += 4) {
        float h0 = __builtin_bit_cast(float, __builtin_amdgcn_readlane(hb, p));
        float h1 = __builtin_bit_cast(float, __builtin_amdgcn_readlane(hb, p + 1));
        float h2 = __builtin_bit_cast(float, __builtin_amdgcn_readlane(hb, p + 2));
        float h3 = __builtin_bit_cast(float, __builtin_amdgcn_readlane(hb, p + 3));
        a0 = fmaf(wreg[p],     h0, a0);
        a1 = fmaf(wreg[p + 1], h1, a1);
        a2 = fmaf(wreg[p + 2], h2, a2);
        a3 = fmaf(wreg[p + 3], h3, a3);
      }
    }
    part[t & 1][wave][lane] = (a0 + a1) + (a2 + a3);
    __syncthreads();   // the ONE barrier per step

    // per-wave finish of row j = jbase + wave
    float zsum = part[t & 1][q][(gi << 4) + wave];
    if (q == 0) zsum += zxv;                 // inject zx once per gi-class
    zsum += __shfl_xor(zsum, 4, 64);
    zsum += __shfl_xor(zsum, 8, 64);
    zsum += __shfl_xor(zsum, 16, 64);
    zsum += __shfl_xor(zsum, 32, 64);        // sum over q (lane bits 2..5)
    float sg = sigm(zsum + ((gi == 2) ? 1.0f : 0.0f));   // FORGET_BIAS on f
    float nl = (gi == 1) ? tanh_fast(zsum) : sg;
    float i_ = rlane(nl, 0);
    float ci_ = rlane(nl, 1);
    float f_ = rlane(nl, 2);
    float o_ = rlane(nl, 3);
    float cs = fmaf(f_, c_reg, i_ * ci_);
    cs = fminf(3.0f, fmaxf(-3.0f, cs));      // CELL_CLIP
    c_reg = cs;                               // uniform per wave
    float h = o_ * tanh_fast(cs);
    if (lane == 0) {
      if (t + 1 < T_STEPS) {
        unsigned pk = ((unsigned)(t + 1) << 16) | (unsigned)f2bf(h);
        __hip_atomic_store(&hcd[(size_t)t * HDIM + jbase + wave], pk,
                           __ATOMIC_RELAXED, __HIP_MEMORY_SCOPE_AGENT);
      }
      hrow[(size_t)t * HDIM + jbase + wave] = h;   // f32 output, fire-and-forget
    }
    // no trailing barrier: part is parity-double-buffered
  }
}

// ---------------------------------------------------------------------------
// launch
// ---------------------------------------------------------------------------
extern "C" void kernel_launch(void* const* d_in, const int* in_sizes, int n_in,
                              void* d_out, int out_size, void* d_ws, size_t ws_size,
                              hipStream_t stream) {
  const float* rf = (const float*)d_in[0];   // res_for_1  [1][4096][1024]
  const float* rb = (const float*)d_in[1];   // res_back_1 [1][4096][1024]
  const float* w  = (const float*)d_in[2];   // w [3072][4096]
  float* out = (float*)d_out;                // [2][4096][1024]

  char* ws = (char*)d_ws;
  unsigned short* zx  = (unsigned short*)ws;                          // [0, 64 MiB)
  unsigned short* xs  = (unsigned short*)(ws + (64u << 20));          // [64, 96 MiB)
  unsigned*      hcom = (unsigned*)(ws + (64u << 20));                // aliases xs (dead after gemm)
  unsigned short* wxT = (unsigned short*)(ws + (96u << 20));          // [96, 112 MiB)

  build_xs<<<16384, 256, 0, stream>>>(rf, rb, xs);
  transpose_wx<<<2048, 256, 0, stream>>>(w, wxT);
  gemm_zx<<<2048, 256, 0, stream>>>(xs, wxT, zx);
  clear_hcom<<<8192, 256, 0, stream>>>((uint4*)hcom);   // zero tags, stream-ordered
  lstm_rec<<<128, 1024, 0, stream>>>(zx, w, out, hcom);
}

// Round 5
// 7739.112 us; speedup vs baseline: 2.1193x; 2.1193x over previous
//
#include <hip/hip_runtime.h>

#define T_STEPS 4096
#define HDIM 1024

typedef __bf16 bf16x8 __attribute__((ext_vector_type(8)));
typedef float f32x4 __attribute__((ext_vector_type(4)));

__device__ __forceinline__ unsigned short f2bf(float x) {
  unsigned u = __builtin_bit_cast(unsigned, x);
  u += 0x7fffu + ((u >> 16) & 1u);   // RNE
  return (unsigned short)(u >> 16);
}
__device__ __forceinline__ float bf2f(unsigned short b) {
  unsigned u = ((unsigned)b) << 16;
  return __builtin_bit_cast(float, u);
}

// ---------------------------------------------------------------------------
// Kernel 1: build xs_bf16 [2][4096][2048] from res_for / res_back.
// ---------------------------------------------------------------------------
__global__ __launch_bounds__(256) void build_xs(
    const float* __restrict__ rf, const float* __restrict__ rb,
    unsigned short* __restrict__ xs) {
  int idx = blockIdx.x * 256 + threadIdx.x;   // one thread per 4 elems
  int e = idx * 4;
  int f = e & 2047;
  int td = e >> 11;
  int t = td & 4095;
  int d = td >> 12;
  bool lower = f < 1024;
  int f2 = f & 1023;
  int trow;
  if (d == 0) trow = lower ? t : (4095 - t);
  else        trow = lower ? (4095 - t) : t;
  const float* src = (lower ? rf : rb) + trow * 1024 + f2;
  float4 v = *(const float4*)src;
  ushort4 o = make_ushort4(f2bf(v.x), f2bf(v.y), f2bf(v.z), f2bf(v.w));
  *(ushort4*)(xs + e) = o;
}

// ---------------------------------------------------------------------------
// Kernel 2: wxT_bf16 [4096 g][2048 f] = transpose of w[:2048].
// ---------------------------------------------------------------------------
__global__ __launch_bounds__(256) void transpose_wx(
    const float* __restrict__ w, unsigned short* __restrict__ wxT) {
  __shared__ float tile[64][65];
  int bid = blockIdx.x;          // 2048 = 32 (f) * 64 (g)
  int bf_ = bid / 64;
  int bg = bid % 64;
  int f0 = bf_ * 64, g0 = bg * 64;
  int tid = threadIdx.x;
#pragma unroll
  for (int s = 0; s < 16; ++s) {
    int idx = s * 256 + tid;
    int fl = idx >> 6, gl = idx & 63;
    tile[fl][gl] = w[(size_t)(f0 + fl) * 4096 + g0 + gl];
  }
  __syncthreads();
#pragma unroll
  for (int s = 0; s < 16; ++s) {
    int idx = s * 256 + tid;
    int gl = idx >> 6, fl = idx & 63;
    wxT[(size_t)(g0 + gl) * 2048 + f0 + fl] = f2bf(tile[fl][gl]);
  }
}

// ---------------------------------------------------------------------------
// Kernel 3: zx = xs @ wx -> bf16 [8192][4096]. 128x128 tile, BK=32, 4 waves.
// ---------------------------------------------------------------------------
__global__ __launch_bounds__(256) void gemm_zx(
    const unsigned short* __restrict__ xs, const unsigned short* __restrict__ wxT,
    unsigned short* __restrict__ zxo) {
  __shared__ uint4 lds[1024];   // A: bytes [0,8192), B: [8192,16384)
  char* ldsb = (char*)lds;
  int bid = blockIdx.x;
  int by = bid >> 5;
  int bx = bid & 31;
  int tid = threadIdx.x, lane = tid & 63, wid = tid >> 6;
  int wr = wid >> 1, wc = wid & 1;
  const int arow0 = by * 128, bcol0 = bx * 128;

  f32x4 acc[4][4] = {};

  for (int kt = 0; kt < 64; ++kt) {
    int k0 = kt * 32;
#pragma unroll
    for (int s = 0; s < 2; ++s) {
      int c = tid + 256 * s;
      int L = c * 16;
      int P = L ^ (((L >> 6) & 7) << 4);
      int row = c >> 2, ko = (c & 3) * 8;
      uint4 av = *(const uint4*)(xs  + (size_t)(arow0 + row) * 2048 + k0 + ko);
      uint4 bv = *(const uint4*)(wxT + (size_t)(bcol0 + row) * 2048 + k0 + ko);
      *(uint4*)(ldsb + P) = av;
      *(uint4*)(ldsb + 8192 + P) = bv;
    }
    __syncthreads();

    bf16x8 afr[4], bfr[4];
#pragma unroll
    for (int i = 0; i < 4; ++i) {
      int arow = wr * 64 + i * 16 + (lane & 15);
      int L = arow * 64 + (lane >> 4) * 16;
      int P = L ^ ((arow & 7) << 4);
      afr[i] = *(bf16x8*)(ldsb + P);
      int brow = wc * 64 + i * 16 + (lane & 15);
      int L2 = brow * 64 + (lane >> 4) * 16;
      int P2 = L2 ^ ((brow & 7) << 4);
      bfr[i] = *(bf16x8*)(ldsb + 8192 + P2);
    }
#pragma unroll
    for (int mi = 0; mi < 4; ++mi)
#pragma unroll
      for (int ni = 0; ni < 4; ++ni)
        acc[mi][ni] = __builtin_amdgcn_mfma_f32_16x16x32_bf16(
            afr[mi], bfr[ni], acc[mi][ni], 0, 0, 0);
    __syncthreads();
  }

#pragma unroll
  for (int mi = 0; mi < 4; ++mi)
#pragma unroll
    for (int ni = 0; ni < 4; ++ni)
#pragma unroll
      for (int r = 0; r < 4; ++r) {
        int rrow = arow0 + wr * 64 + mi * 16 + (lane >> 4) * 4 + r;
        int col  = bcol0 + wc * 64 + ni * 16 + (lane & 15);
        zxo[(size_t)rrow * 4096 + col] = f2bf(acc[mi][ni][r]);
      }
}

// ---------------------------------------------------------------------------
// Kernel 3.5: clear hcom tags (aliases dead xs region; runs after gemm).
// ---------------------------------------------------------------------------
__global__ __launch_bounds__(256) void clear_hcom(uint4* __restrict__ p) {
  p[(size_t)blockIdx.x * 256 + threadIdx.x] = uint4{0, 0, 0, 0};
}

// ---------------------------------------------------------------------------
// Kernel 4: persistent recurrent LSTM (R3 structure + pre-issued poll sample
// + store split wave0/wave1). 128 blocks (64/dir) x 1024 threads.
//   - packed h exchange: u32 = (t+1)<<16 | bf16(h); poll IS the data load
//   - wave w polls its own 64-elem k-slice; LDS h-stage; broadcast matvec
//   - part[2][16][64] parity-buffered; ONE barrier per step
//   - wave0 tail: gates + CRITICAL hcom store; wave1: identical gate math
//     (same FP ops, same c chain) + non-critical f32 hrow store
// ---------------------------------------------------------------------------
__device__ __forceinline__ float sigm(float x) {
  return 1.0f / (1.0f + __expf(-x));
}
__device__ __forceinline__ float tanh_fast(float x) {
  float e = __expf(-2.0f * x);
  return (1.0f - e) / (1.0f + e);
}

__global__ __launch_bounds__(1024, 4) void lstm_rec(
    const unsigned short* __restrict__ zx,  // [2][4096][4096] bf16
    const float* __restrict__ w,            // [3072][4096] f32 (w_h = rows 2048+)
    float* __restrict__ hout,               // d_out [2][4096][1024] f32
    unsigned* __restrict__ hcom) {          // [2][4096][1024] packed tag|bf16h
  __shared__ float4 h4[16][16];             // per-wave 64 f32 h slice
  __shared__ float part[2][16][64];         // parity-double-buffered partials

  int bid = blockIdx.x;
  int dir = bid >> 6;
  int bslot = bid & 63;
  int jbase = bslot << 4;                   // 16 j's per block
  int tid = threadIdx.x;
  int wave = tid >> 6;                      // k-slice: wave*64..+63
  int lane = tid & 63;                      // column: jj = lane&15, gate = lane>>4
  int jj = lane & 15, g = lane >> 4;
  int gcol = (g << 10) + jbase + jj;

  // preload W_h slice: w[(2048 + wave*64 + p)][gcol]  (f32, exact)
  float wreg[64];
#pragma unroll
  for (int p = 0; p < 64; ++p)
    wreg[p] = w[(size_t)(2048 + wave * 64 + p) * 4096 + gcol];
#pragma unroll
  for (int p = 0; p < 64; ++p) asm volatile("" : "+v"(wreg[p]));

  float c_reg = 0.0f;
  const unsigned short* zrow = zx + (size_t)dir * T_STEPS * 4096;
  float* hrow = hout + (size_t)dir * T_STEPS * HDIM;
  unsigned* hcd = hcom + (size_t)dir * T_STEPS * HDIM;
  const unsigned* hp_slice = hcd + wave * 64 + lane;   // + t*HDIM per step

  unsigned pre = 0;                         // pre-issued poll sample for step t

  for (int t = 0; t < T_STEPS; ++t) {
    // wave15 owns the zx contribution (keeps wave0's critical path short)
    float zxv = 0.0f;
    if (wave == 15) zxv = bf2f(zrow[(size_t)t * 4096 + gcol]);

    // poll own 64-element k-slice of h_{t-1}; the poll IS the h load.
    // tag monotone {0, t<<16|bf16}, so unsigned < works; 'pre' was issued
    // before last step's barrier and may already satisfy the check.
    float hv = 0.0f;
    if (t > 0) {
      const unsigned* hp = hp_slice + (size_t)(t - 1) * HDIM;
      unsigned want = (unsigned)t << 16;
      unsigned v = pre;
      while (v < want)
        v = __hip_atomic_load(hp, __ATOMIC_RELAXED, __HIP_MEMORY_SCOPE_AGENT);
      hv = __builtin_bit_cast(float, v << 16);
    }
    ((float*)&h4[wave][0])[lane] = hv;
    asm volatile("s_waitcnt lgkmcnt(0)" ::: "memory");

    // per-wave partial dot: 64 FMA over broadcast LDS reads
    float a0 = 0.f, a1 = 0.f, a2 = 0.f, a3 = 0.f;
#pragma unroll
    for (int q = 0; q < 16; ++q) {
      float4 x = h4[wave][q];
      a0 = fmaf(wreg[4 * q + 0], x.x, a0);
      a1 = fmaf(wreg[4 * q + 1], x.y, a1);
      a2 = fmaf(wreg[4 * q + 2], x.z, a2);
      a3 = fmaf(wreg[4 * q + 3], x.w, a3);
    }
    float psum = (a0 + a1) + (a2 + a3);
    if (wave == 15) psum += zxv;
    part[t & 1][wave][lane] = psum;

    // pre-issue next step's first poll sample (in flight across the barrier)
    if (t + 1 < T_STEPS)
      pre = __hip_atomic_load(hp_slice + (size_t)t * HDIM,
                              __ATOMIC_RELAXED, __HIP_MEMORY_SCOPE_AGENT);

    __syncthreads();   // the ONE barrier per step

    // tails: wave0 (critical, hcom) and wave1 (duplicate math, hrow).
    // Identical FP ops in both waves -> identical c chains, deterministic.
    if (wave <= 1) {
      float z = 0.f;
#pragma unroll
      for (int q = 0; q < 16; ++q) z += part[t & 1][q][lane];
      float gz = (g == 2) ? z + 1.0f : z;       // FORGET_BIAS on f gate
      float nl = (g == 1) ? tanh_fast(z) : sigm(gz);
      float iv = __shfl(nl, jj, 64);
      float cv = __shfl(nl, 16 + jj, 64);
      float fv = __shfl(nl, 32 + jj, 64);
      float ov = __shfl(nl, 48 + jj, 64);
      if (lane < 16) {
        float cs = fmaf(fv, c_reg, iv * cv);
        cs = fminf(3.0f, fmaxf(-3.0f, cs));     // CELL_CLIP
        c_reg = cs;
        float h = ov * tanh_fast(cs);
        if (wave == 0) {
          if (t + 1 < T_STEPS) {
            unsigned pk = ((unsigned)(t + 1) << 16) | (unsigned)f2bf(h);
            __hip_atomic_store(&hcd[(size_t)t * HDIM + jbase + lane], pk,
                               __ATOMIC_RELAXED, __HIP_MEMORY_SCOPE_AGENT);
          }
        } else {
          hrow[(size_t)t * HDIM + jbase + lane] = h;   // f32 output
        }
      }
    }
    // no trailing barrier: part is parity-double-buffered
  }
}

// ---------------------------------------------------------------------------
// launch
// ---------------------------------------------------------------------------
extern "C" void kernel_launch(void* const* d_in, const int* in_sizes, int n_in,
                              void* d_out, int out_size, void* d_ws, size_t ws_size,
                              hipStream_t stream) {
  const float* rf = (const float*)d_in[0];   // res_for_1  [1][4096][1024]
  const float* rb = (const float*)d_in[1];   // res_back_1 [1][4096][1024]
  const float* w  = (const float*)d_in[2];   // w [3072][4096]
  float* out = (float*)d_out;                // [2][4096][1024]

  char* ws = (char*)d_ws;
  unsigned short* zx  = (unsigned short*)ws;                          // [0, 64 MiB)
  unsigned short* xs  = (unsigned short*)(ws + (64u << 20));          // [64, 96 MiB)
  unsigned*      hcom = (unsigned*)(ws + (64u << 20));                // aliases xs (dead after gemm)
  unsigned short* wxT = (unsigned short*)(ws + (96u << 20));          // [96, 112 MiB)

  build_xs<<<16384, 256, 0, stream>>>(rf, rb, xs);
  transpose_wx<<<2048, 256, 0, stream>>>(w, wxT);
  gemm_zx<<<2048, 256, 0, stream>>>(xs, wxT, zx);
  clear_hcom<<<8192, 256, 0, stream>>>((uint4*)hcom);   // zero tags, stream-ordered
  lstm_rec<<<128, 1024, 0, stream>>>(zx, w, out, hcom);
}

// Round 6
// 6339.260 us; speedup vs baseline: 2.5873x; 1.2208x over previous
//
#include <hip/hip_runtime.h>

#define T_STEPS 4096
#define HDIM 1024

typedef __bf16 bf16x8 __attribute__((ext_vector_type(8)));
typedef float f32x4 __attribute__((ext_vector_type(4)));
typedef _Float16 half2_t __attribute__((ext_vector_type(2)));

__device__ __forceinline__ unsigned short f2bf(float x) {
  unsigned u = __builtin_bit_cast(unsigned, x);
  u += 0x7fffu + ((u >> 16) & 1u);   // RNE
  return (unsigned short)(u >> 16);
}
__device__ __forceinline__ float bf2f(unsigned short b) {
  unsigned u = ((unsigned)b) << 16;
  return __builtin_bit_cast(float, u);
}

// ---------------------------------------------------------------------------
// Kernel 1: build xs_bf16 [2][4096][2048] from res_for / res_back.
// ---------------------------------------------------------------------------
__global__ __launch_bounds__(256) void build_xs(
    const float* __restrict__ rf, const float* __restrict__ rb,
    unsigned short* __restrict__ xs) {
  int idx = blockIdx.x * 256 + threadIdx.x;   // one thread per 4 elems
  int e = idx * 4;
  int f = e & 2047;
  int td = e >> 11;
  int t = td & 4095;
  int d = td >> 12;
  bool lower = f < 1024;
  int f2 = f & 1023;
  int trow;
  if (d == 0) trow = lower ? t : (4095 - t);
  else        trow = lower ? (4095 - t) : t;
  const float* src = (lower ? rf : rb) + trow * 1024 + f2;
  float4 v = *(const float4*)src;
  ushort4 o = make_ushort4(f2bf(v.x), f2bf(v.y), f2bf(v.z), f2bf(v.w));
  *(ushort4*)(xs + e) = o;
}

// ---------------------------------------------------------------------------
// Kernel 2: wxT_bf16 [4096 g][2048 f] = transpose of w[:2048].
// ---------------------------------------------------------------------------
__global__ __launch_bounds__(256) void transpose_wx(
    const float* __restrict__ w, unsigned short* __restrict__ wxT) {
  __shared__ float tile[64][65];
  int bid = blockIdx.x;          // 2048 = 32 (f) * 64 (g)
  int bf_ = bid / 64;
  int bg = bid % 64;
  int f0 = bf_ * 64, g0 = bg * 64;
  int tid = threadIdx.x;
#pragma unroll
  for (int s = 0; s < 16; ++s) {
    int idx = s * 256 + tid;
    int fl = idx >> 6, gl = idx & 63;
    tile[fl][gl] = w[(size_t)(f0 + fl) * 4096 + g0 + gl];
  }
  __syncthreads();
#pragma unroll
  for (int s = 0; s < 16; ++s) {
    int idx = s * 256 + tid;
    int gl = idx >> 6, fl = idx & 63;
    wxT[(size_t)(g0 + gl) * 2048 + f0 + fl] = f2bf(tile[fl][gl]);
  }
}

// ---------------------------------------------------------------------------
// Kernel 3: zx = xs @ wx -> bf16 [8192][4096]. 128x128 tile, BK=32, 4 waves.
// ---------------------------------------------------------------------------
__global__ __launch_bounds__(256) void gemm_zx(
    const unsigned short* __restrict__ xs, const unsigned short* __restrict__ wxT,
    unsigned short* __restrict__ zxo) {
  __shared__ uint4 lds[1024];   // A: bytes [0,8192), B: [8192,16384)
  char* ldsb = (char*)lds;
  int bid = blockIdx.x;
  int by = bid >> 5;
  int bx = bid & 31;
  int tid = threadIdx.x, lane = tid & 63, wid = tid >> 6;
  int wr = wid >> 1, wc = wid & 1;
  const int arow0 = by * 128, bcol0 = bx * 128;

  f32x4 acc[4][4] = {};

  for (int kt = 0; kt < 64; ++kt) {
    int k0 = kt * 32;
#pragma unroll
    for (int s = 0; s < 2; ++s) {
      int c = tid + 256 * s;
      int L = c * 16;
      int P = L ^ (((L >> 6) & 7) << 4);
      int row = c >> 2, ko = (c & 3) * 8;
      uint4 av = *(const uint4*)(xs  + (size_t)(arow0 + row) * 2048 + k0 + ko);
      uint4 bv = *(const uint4*)(wxT + (size_t)(bcol0 + row) * 2048 + k0 + ko);
      *(uint4*)(ldsb + P) = av;
      *(uint4*)(ldsb + 8192 + P) = bv;
    }
    __syncthreads();

    bf16x8 afr[4], bfr[4];
#pragma unroll
    for (int i = 0; i < 4; ++i) {
      int arow = wr * 64 + i * 16 + (lane & 15);
      int L = arow * 64 + (lane >> 4) * 16;
      int P = L ^ ((arow & 7) << 4);
      afr[i] = *(bf16x8*)(ldsb + P);
      int brow = wc * 64 + i * 16 + (lane & 15);
      int L2 = brow * 64 + (lane >> 4) * 16;
      int P2 = L2 ^ ((brow & 7) << 4);
      bfr[i] = *(bf16x8*)(ldsb + 8192 + P2);
    }
#pragma unroll
    for (int mi = 0; mi < 4; ++mi)
#pragma unroll
      for (int ni = 0; ni < 4; ++ni)
        acc[mi][ni] = __builtin_amdgcn_mfma_f32_16x16x32_bf16(
            afr[mi], bfr[ni], acc[mi][ni], 0, 0, 0);
    __syncthreads();
  }

#pragma unroll
  for (int mi = 0; mi < 4; ++mi)
#pragma unroll
    for (int ni = 0; ni < 4; ++ni)
#pragma unroll
      for (int r = 0; r < 4; ++r) {
        int rrow = arow0 + wr * 64 + mi * 16 + (lane >> 4) * 4 + r;
        int col  = bcol0 + wc * 64 + ni * 16 + (lane & 15);
        zxo[(size_t)rrow * 4096 + col] = f2bf(acc[mi][ni][r]);
      }
}

// ---------------------------------------------------------------------------
// Kernel 3.25: pack W_h as f16 pairs: whp[k2][4096 g] u32 = (f16(w_h[2k2+1][g])<<16)
//              | f16(w_h[2k2][g]).  w_h = w rows 2048..3071.
// ---------------------------------------------------------------------------
__global__ __launch_bounds__(256) void pack_whp(
    const float* __restrict__ w, unsigned* __restrict__ whp) {
  int idx = blockIdx.x * 256 + threadIdx.x;   // [0, 512*4096)
  int gc = idx & 4095;
  int k2 = idx >> 12;
  float w0 = w[(size_t)(2048 + 2 * k2) * 4096 + gc];
  float w1 = w[(size_t)(2048 + 2 * k2 + 1) * 4096 + gc];
  unsigned short a = __builtin_bit_cast(unsigned short, (_Float16)w0);
  unsigned short b = __builtin_bit_cast(unsigned short, (_Float16)w1);
  whp[idx] = ((unsigned)b << 16) | (unsigned)a;
}

// ---------------------------------------------------------------------------
// Kernel 3.5: clear hcom tags (aliases dead xs region; runs after gemm).
// ---------------------------------------------------------------------------
__global__ __launch_bounds__(256) void clear_hcom(uint4* __restrict__ p) {
  p[(size_t)blockIdx.x * 256 + threadIdx.x] = uint4{0, 0, 0, 0};
}

// ---------------------------------------------------------------------------
// Kernel 4: persistent recurrent LSTM. 128 blocks (64/dir) x 1024 threads.
//   - W_h register-resident: 32 packed-f16-pair u32 per thread, laundered
//     through volatile v_mov so the compiler cannot rematerialize the loads
//     (R2-R5: VGPR_Count=52 proved f32 wreg was re-streamed from L2 = ~half
//     the step time).
//   - matvec: 32 x v_dot2_f32_f16 against h-pairs broadcast from LDS stage.
//   - h exchange: packed u32 = (t+1)<<16 | f16(h); poll IS the data load.
//   - part[2][16][64] parity-buffered; ONE barrier per step; wave0 tail.
// ---------------------------------------------------------------------------
__device__ __forceinline__ float sigm(float x) {
  return 1.0f / (1.0f + __expf(-x));
}
__device__ __forceinline__ float tanh_fast(float x) {
  float e = __expf(-2.0f * x);
  return (1.0f - e) / (1.0f + e);
}

__global__ __launch_bounds__(1024, 4) void lstm_rec(
    const unsigned short* __restrict__ zx,  // [2][4096][4096] bf16
    const unsigned* __restrict__ whp,       // [512][4096] packed f16-pair W_h
    float* __restrict__ hout,               // d_out [2][4096][1024] f32
    unsigned* __restrict__ hcom) {          // [2][4096][1024] packed tag|f16h
  __shared__ unsigned short hstg[16][64];   // per-wave h f16 stage (128B rows)
  __shared__ float part[2][16][64];         // parity-double-buffered partials

  int bid = blockIdx.x;
  int dir = bid >> 6;
  int bslot = bid & 63;
  int jbase = bslot << 4;                   // 16 j's per block
  int tid = threadIdx.x;
  int wave = tid >> 6;                      // k-slice: wave*64..+63
  int lane = tid & 63;                      // column: jj = lane&15, gate = lane>>4
  int jj = lane & 15, g = lane >> 4;
  int gcol = (g << 10) + jbase + jj;

  // ---- W_h slice into registers: 32 u32 (64 f16), opaque-laundered ----
  unsigned wpk[32];
  {
    const unsigned* wp = whp + (size_t)(wave * 32) * 4096 + gcol;
#pragma unroll
    for (int i = 0; i < 32; ++i) wpk[i] = wp[(size_t)i * 4096];
#pragma unroll
    for (int i = 0; i < 32; ++i)
      asm volatile("v_mov_b32 %0, %0" : "+v"(wpk[i]));  // non-rematerializable
  }

  float c_reg = 0.0f;
  const unsigned short* zrow = zx + (size_t)dir * T_STEPS * 4096;
  float* hrow = hout + (size_t)dir * T_STEPS * HDIM;
  unsigned* hcd = hcom + (size_t)dir * T_STEPS * HDIM;
  const unsigned* hp_slice = hcd + wave * 64 + lane;   // + t*HDIM per step

  for (int t = 0; t < T_STEPS; ++t) {
    // wave15 owns the zx contribution (keeps wave0's critical path short)
    float zxv = 0.0f;
    if (wave == 15) zxv = bf2f(zrow[(size_t)t * 4096 + gcol]);

    // poll own 64-element k-slice of h_{t-1}; the poll IS the h load.
    // tag monotone {0, t<<16|f16}, so unsigned < works.
    unsigned short hbits = 0;
    if (t > 0) {
      const unsigned* hp = hp_slice + (size_t)(t - 1) * HDIM;
      unsigned want = (unsigned)t << 16;
      unsigned v;
      do {
        v = __hip_atomic_load(hp, __ATOMIC_RELAXED, __HIP_MEMORY_SCOPE_AGENT);
      } while (v < want);
      hbits = (unsigned short)v;            // f16 payload
    }
    hstg[wave][lane] = hbits;
    asm volatile("s_waitcnt lgkmcnt(0)" ::: "memory");  // wave-local stage done

    // matvec: 32 x dot2 (f16 pairs, f32 accum); h2 reads are same-address
    // broadcasts within the wave (conflict-free).
    const unsigned* h2 = (const unsigned*)(&hstg[wave][0]);
    float acc = 0.0f;
#pragma unroll
    for (int i = 0; i < 32; ++i) {
      half2_t hh = __builtin_bit_cast(half2_t, h2[i]);
      half2_t ww = __builtin_bit_cast(half2_t, wpk[i]);
      acc = __builtin_amdgcn_fdot2(ww, hh, acc, false);
    }
    if (wave == 15) acc += zxv;
    part[t & 1][wave][lane] = acc;
    __syncthreads();   // the ONE barrier per step

    // wave0 tail: reduce 16 partials, gates, both stores
    if (wave == 0) {
      float z = 0.f;
#pragma unroll
      for (int q = 0; q < 16; ++q) z += part[t & 1][q][lane];
      float gz = (g == 2) ? z + 1.0f : z;       // FORGET_BIAS on f gate
      float nl = (g == 1) ? tanh_fast(z) : sigm(gz);
      float iv = __shfl(nl, jj, 64);
      float cv = __shfl(nl, 16 + jj, 64);
      float fv = __shfl(nl, 32 + jj, 64);
      float ov = __shfl(nl, 48 + jj, 64);
      if (lane < 16) {
        float cs = fmaf(fv, c_reg, iv * cv);
        cs = fminf(3.0f, fmaxf(-3.0f, cs));     // CELL_CLIP
        c_reg = cs;
        float h = ov * tanh_fast(cs);
        if (t + 1 < T_STEPS) {
          unsigned short hb = __builtin_bit_cast(unsigned short, (_Float16)h);
          unsigned pk = ((unsigned)(t + 1) << 16) | (unsigned)hb;
          __hip_atomic_store(&hcd[(size_t)t * HDIM + jbase + lane], pk,
                             __ATOMIC_RELAXED, __HIP_MEMORY_SCOPE_AGENT);
        }
        hrow[(size_t)t * HDIM + jbase + lane] = h;   // f32 output
      }
    }
    // no trailing barrier: part is parity-double-buffered
  }
}

// ---------------------------------------------------------------------------
// launch
// ---------------------------------------------------------------------------
extern "C" void kernel_launch(void* const* d_in, const int* in_sizes, int n_in,
                              void* d_out, int out_size, void* d_ws, size_t ws_size,
                              hipStream_t stream) {
  const float* rf = (const float*)d_in[0];   // res_for_1  [1][4096][1024]
  const float* rb = (const float*)d_in[1];   // res_back_1 [1][4096][1024]
  const float* w  = (const float*)d_in[2];   // w [3072][4096]
  float* out = (float*)d_out;                // [2][4096][1024]

  char* ws = (char*)d_ws;
  unsigned short* zx  = (unsigned short*)ws;                          // [0, 64 MiB)
  unsigned short* xs  = (unsigned short*)(ws + (64u << 20));          // [64, 96 MiB)
  unsigned*      hcom = (unsigned*)(ws + (64u << 20));                // aliases xs (dead after gemm)
  unsigned short* wxT = (unsigned short*)(ws + (96u << 20));          // [96, 112 MiB)
  unsigned*      whp  = (unsigned*)(ws + (96u << 20));                // aliases wxT (dead after gemm)

  build_xs<<<16384, 256, 0, stream>>>(rf, rb, xs);
  transpose_wx<<<2048, 256, 0, stream>>>(w, wxT);
  gemm_zx<<<2048, 256, 0, stream>>>(xs, wxT, zx);
  pack_whp<<<8192, 256, 0, stream>>>(w, whp);           // after gemm: wxT dead
  clear_hcom<<<8192, 256, 0, stream>>>((uint4*)hcom);   // zero tags (32 MiB)
  lstm_rec<<<128, 1024, 0, stream>>>(zx, whp, out, hcom);
}